// Round 4
// baseline (394.112 us; speedup 1.0000x reference)
//
#include <hip/hip_runtime.h>
#include <hip/hip_bf16.h>
#include <hip/hip_fp16.h>

#define N_NODES 100000
#define DFEAT 128
#define SLAB 4096         // edges per partition block
#define BSHIFT 9          // 512 nodes per bucket
#define NBUCK 196         // ceil(100000/512)

// ---------------- ws layout (4-byte units) ----------------
// cnt    [0      , 100000)   written by phase3 (no memset needed)
// gh     [100000 , 176636)   bucket-major (bucket,block) histogram -> scanned bases
// partialB[180000, 180512)
// zrow   [180512 , 180576)   256 B of zeros (invalid-gather target), written by prep
// offs   [200000 , 300096)   written by phase3
// esrc   [300608 , 1900608)
// aggh   [1900608, 8300608)   first: int2 pairs buffer; then fp16 h (layer-1 out)
// casth  [8300608, 14700608)  fp16 x_h
#define WS_CNT      0
#define WS_GH       100000
#define WS_PARTB    180000
#define WS_ZROW     180512
#define WS_OFFS     200000
#define WS_ESRC     300608
#define WS_AGGH     1900608
#define WS_CASTH    8300608

typedef _Float16 half8 __attribute__((ext_vector_type(8)));
typedef float floatx4 __attribute__((ext_vector_type(4)));

// ---------- fused prep: cast x->fp16 (blocks < castblocks) + slab bucket hist ----------
__global__ __launch_bounds__(256) void prep_kernel(const float* __restrict__ x,
                                                   __half* __restrict__ xh, int total4,
                                                   const int* __restrict__ dst,
                                                   int* __restrict__ gh,
                                                   uint2* __restrict__ zrow,
                                                   int E, int bpart, int castblocks) {
    __shared__ int lh[NBUCK];
    int b = blockIdx.x;
    if (b < castblocks) {
        int i = b * 256 + threadIdx.x;
        if (i < total4) {
            float4 v = ((const float4*)x)[i];
            __half2 h01 = __floats2half2_rn(v.x, v.y);
            __half2 h23 = __floats2half2_rn(v.z, v.w);
            uint2 o;
            o.x = *(unsigned int*)&h01;
            o.y = *(unsigned int*)&h23;
            ((uint2*)xh)[i] = o;
        }
        return;
    }
    int bb = b - castblocks;
    // one block also zeroes the 256 B zero-row used by fused gather for invalid slots
    if (bb == 0 && threadIdx.x < 32) zrow[threadIdx.x] = make_uint2(0u, 0u);
    for (int i = threadIdx.x; i < NBUCK; i += 256) lh[i] = 0;
    __syncthreads();
    int s0 = bb * SLAB, s1 = min(E, s0 + SLAB);
    for (int i = s0 + threadIdx.x; i < s1; i += 256)
        atomicAdd(&lh[dst[i] >> BSHIFT], 1);
    __syncthreads();
    for (int i = threadIdx.x; i < NBUCK; i += 256) gh[i * bpart + bb] = lh[i];
}

// ---------- exclusive-scan trio over gh (in-place) ----------
__global__ void scan1_kernel(int* __restrict__ gh, int* __restrict__ partial, int m) {
    __shared__ int s[256];
    int i = blockIdx.x * 256 + threadIdx.x;
    int v = (i < m) ? gh[i] : 0;
    s[threadIdx.x] = v;
    __syncthreads();
    for (int d = 1; d < 256; d <<= 1) {
        int t = (threadIdx.x >= d) ? s[threadIdx.x - d] : 0;
        __syncthreads();
        s[threadIdx.x] += t;
        __syncthreads();
    }
    int incl = s[threadIdx.x];
    if (i < m) gh[i] = incl - v;
    if (threadIdx.x == 255) partial[blockIdx.x] = incl;
}

__global__ void scan2_kernel(int* __restrict__ partial, int nb) {
    __shared__ int s[512];
    int t = threadIdx.x;
    int v = (t < nb) ? partial[t] : 0;
    s[t] = v;
    __syncthreads();
    for (int d = 1; d < 512; d <<= 1) {
        int u = (t >= d) ? s[t - d] : 0;
        __syncthreads();
        s[t] += u;
        __syncthreads();
    }
    if (t < nb) partial[t] = s[t] - v;
}

__global__ void scan3_kernel(int* __restrict__ gh, const int* __restrict__ partial, int m) {
    int i = blockIdx.x * 256 + threadIdx.x;
    if (i < m) gh[i] += partial[blockIdx.x];
}

// ---------- phase 2: LDS counting-sort slab by bucket, copy runs out ----------
__global__ __launch_bounds__(256) void phase2_kernel(const int* __restrict__ src,
                                                     const int* __restrict__ dst,
                                                     const int* __restrict__ gbase,
                                                     int2* __restrict__ pairs,
                                                     int E, int bpart) {
    __shared__ int lbase[NBUCK];
    __shared__ int lcur[NBUCK];
    __shared__ int lgb[NBUCK];
    __shared__ int sc[256];
    __shared__ int2 lp[SLAB];   // 32 KB
    int b = blockIdx.x;
    int t = threadIdx.x;
    for (int i = t; i < NBUCK; i += 256) lbase[i] = 0;
    __syncthreads();
    int s0 = b * SLAB, s1 = min(E, s0 + SLAB);
    for (int i = s0 + t; i < s1; i += 256)
        atomicAdd(&lbase[dst[i] >> BSHIFT], 1);
    __syncthreads();
    int v = (t < NBUCK) ? lbase[t] : 0;
    sc[t] = v;
    __syncthreads();
    for (int d = 1; d < 256; d <<= 1) {
        int u = (t >= d) ? sc[t - d] : 0;
        __syncthreads();
        sc[t] += u;
        __syncthreads();
    }
    if (t < NBUCK) {
        int excl = sc[t] - v;
        lbase[t] = excl;
        lcur[t] = excl;
        lgb[t] = gbase[t * bpart + b];
    }
    __syncthreads();
    for (int i = s0 + t; i < s1; i += 256) {
        int d = dst[i];
        int s = src[i];
        int bk = d >> BSHIFT;
        int pos = atomicAdd(&lcur[bk], 1);
        lp[pos] = make_int2(s, d);
    }
    __syncthreads();
    int m = s1 - s0;
    for (int i = t; i < m; i += 256) {
        int2 p = lp[i];
        int bk = p.y >> BSHIFT;
        pairs[lgb[bk] + (i - lbase[bk])] = p;
    }
}

// ---------- phase 3: per-bucket node hist (LDS) + scan -> cnt/offs + CSR finalize ----------
__global__ __launch_bounds__(512) void phase3_kernel(const int2* __restrict__ pairs,
                                                     const int* __restrict__ gbase,
                                                     int* __restrict__ cnt,
                                                     int* __restrict__ offs,
                                                     int* __restrict__ esrc,
                                                     int E, int bpart, int n) {
    __shared__ int lcnt[512];
    __shared__ int sc[512];
    __shared__ int lexcl[512];
    int g = blockIdx.x;
    int node0 = g << BSHIFT;
    int t = threadIdx.x;
    lcnt[t] = 0;
    __syncthreads();
    int S = gbase[g * bpart];
    int Eg = (g == NBUCK - 1) ? E : gbase[(g + 1) * bpart];
    for (int i = S + t; i < Eg; i += 512)
        atomicAdd(&lcnt[pairs[i].y - node0], 1);
    __syncthreads();
    int v = lcnt[t];
    sc[t] = v;
    __syncthreads();
    for (int d = 1; d < 512; d <<= 1) {
        int u = (t >= d) ? sc[t - d] : 0;
        __syncthreads();
        sc[t] += u;
        __syncthreads();
    }
    int excl = sc[t] - v;
    lexcl[t] = excl;
    int nd = node0 + t;
    if (nd < n) {
        cnt[nd] = v;
        offs[nd] = S + excl;
    }
    __syncthreads();
    for (int i = S + t; i < Eg; i += 512) {
        int2 p = pairs[i];
        int pos = atomicAdd(&lexcl[p.y - node0], 1);
        esrc[S + pos] = p.x;
    }
}

// ---------- fused layer: gather-aggregate into MFMA B-frags + dual-GEMM + epilogue ----------
// Block = 128 nodes, 4 waves x 32 nodes. Lane (quad,l15): node i0+l15(+16), cols kc*32+quad*8.
// The aggregate accumulates DIRECTLY in the B-fragment register layout the MFMA consumes:
// no agg round-trip through HBM, no separate GEMM dispatch, MFMA hides under the gather wall.
// Invalid edge slots (j >= deg) redirect the load pointer to a 256 B zero-row (L1-hot).
template <bool NORM_RELU>
__global__ __launch_bounds__(256, 4) void fused_layer_kernel(
    const __half* __restrict__ feat_, const int* __restrict__ esrc,
    const int* __restrict__ offs, const int* __restrict__ cnt,
    const float* __restrict__ Wl, const float* __restrict__ Wr,
    const float* __restrict__ bias, const __half* __restrict__ zrow_,
    float* __restrict__ out32, __half* __restrict__ out16, int n) {
    __shared__ __align__(16) _Float16 lw[128 * 136];   // 34.8 KB, one weight at a time

    const _Float16* feat = (const _Float16*)feat_;
    const _Float16* zrow = (const _Float16*)zrow_;

    const int lane = threadIdx.x & 63;
    const int w = threadIdx.x >> 6;
    const int quad = lane >> 4;
    const int l15 = lane & 15;
    const int i0 = blockIdx.x * 128 + w * 32;

    // ---- stage Wl (fp32 -> fp16 LDS) ----
    {
        int t = threadIdx.x;
        int row = t >> 1;
        int cb = (t & 1) * 64;
        const float4* sp = (const float4*)(Wl + row * DFEAT + cb);
        unsigned int* dp = (unsigned int*)&lw[row * 136 + cb];
#pragma unroll
        for (int q = 0; q < 16; q++) {
            float4 v = sp[q];
            __half2 h01 = __floats2half2_rn(v.x, v.y);
            __half2 h23 = __floats2half2_rn(v.z, v.w);
            dp[q * 2] = *(unsigned int*)&h01;
            dp[q * 2 + 1] = *(unsigned int*)&h23;
        }
    }

    // ---- gather-aggregate mean(neigh) into B-fragments ----
    int r0 = i0 + l15;      if (r0 >= n) r0 = n - 1;
    int r1 = i0 + 16 + l15; if (r1 >= n) r1 = n - 1;
    int deg0 = cnt[r0], off0 = offs[r0];
    int deg1 = cnt[r1], off1 = offs[r1];
    int md = max(deg0, deg1);
    md = max(md, __shfl_xor(md, 1));
    md = max(md, __shfl_xor(md, 2));
    md = max(md, __shfl_xor(md, 4));
    md = max(md, __shfl_xor(md, 8));

    const _Float16* fq = feat + quad * 8;
    const _Float16* zq = zrow + quad * 8;

    half8 bf0[4], bf1[4];
#pragma unroll
    for (int k = 0; k < 4; k++) {
        bf0[k] = (half8)(_Float16)0;
        bf1[k] = (half8)(_Float16)0;
    }

    for (int j = 0; j < md; j++) {
        int s0 = esrc[off0 + j];   // bounded garbage ok when j>=deg0 (ptr overridden)
        int s1 = esrc[off1 + j];
        const _Float16* p0 = (j < deg0) ? (fq + (size_t)s0 * DFEAT) : zq;
        const _Float16* p1 = (j < deg1) ? (fq + (size_t)s1 * DFEAT) : zq;
        half8 t00 = *(const half8*)(p0);
        half8 t01 = *(const half8*)(p0 + 32);
        half8 t02 = *(const half8*)(p0 + 64);
        half8 t03 = *(const half8*)(p0 + 96);
        half8 t10 = *(const half8*)(p1);
        half8 t11 = *(const half8*)(p1 + 32);
        half8 t12 = *(const half8*)(p1 + 64);
        half8 t13 = *(const half8*)(p1 + 96);
        bf0[0] += t00; bf0[1] += t01; bf0[2] += t02; bf0[3] += t03;
        bf1[0] += t10; bf1[1] += t11; bf1[2] += t12; bf1[3] += t13;
    }

    // mean scale (fp32 math, repack fp16)
    float sc0 = 1.0f / fmaxf((float)deg0, 1.0f);
    float sc1 = 1.0f / fmaxf((float)deg1, 1.0f);
#pragma unroll
    for (int k = 0; k < 4; k++) {
        half8 a = bf0[k], b = bf1[k];
#pragma unroll
        for (int e = 0; e < 8; e++) {
            a[e] = (_Float16)((float)a[e] * sc0);
            b[e] = (_Float16)((float)b[e] * sc1);
        }
        bf0[k] = a;
        bf1[k] = b;
    }

    __syncthreads();   // Wl visible to all waves

    floatx4 acc[2][8];
#pragma unroll
    for (int nt = 0; nt < 2; nt++)
#pragma unroll
        for (int ft = 0; ft < 8; ft++)
            acc[nt][ft] = (floatx4){0.f, 0.f, 0.f, 0.f};

#pragma unroll
    for (int kci = 0; kci < 4; kci++) {
#pragma unroll
        for (int ft = 0; ft < 8; ft++) {
            half8 a = *(const half8*)&lw[(ft * 16 + l15) * 136 + kci * 32 + quad * 8];
            acc[0][ft] = __builtin_amdgcn_mfma_f32_16x16x32_f16(a, bf0[kci], acc[0][ft], 0, 0, 0);
            acc[1][ft] = __builtin_amdgcn_mfma_f32_16x16x32_f16(a, bf1[kci], acc[1][ft], 0, 0, 0);
        }
    }

    __syncthreads();   // all waves done reading Wl

    // root (self) fragments — issue loads so they fly during Wr staging
    half8 xf0[4], xf1[4];
    {
        const _Float16* xr0 = feat + (size_t)r0 * DFEAT + quad * 8;
        const _Float16* xr1 = feat + (size_t)r1 * DFEAT + quad * 8;
#pragma unroll
        for (int k = 0; k < 4; k++) {
            xf0[k] = *(const half8*)(xr0 + k * 32);
            xf1[k] = *(const half8*)(xr1 + k * 32);
        }
    }

    // ---- stage Wr ----
    {
        int t = threadIdx.x;
        int row = t >> 1;
        int cb = (t & 1) * 64;
        const float4* sp = (const float4*)(Wr + row * DFEAT + cb);
        unsigned int* dp = (unsigned int*)&lw[row * 136 + cb];
#pragma unroll
        for (int q = 0; q < 16; q++) {
            float4 v = sp[q];
            __half2 h01 = __floats2half2_rn(v.x, v.y);
            __half2 h23 = __floats2half2_rn(v.z, v.w);
            dp[q * 2] = *(unsigned int*)&h01;
            dp[q * 2 + 1] = *(unsigned int*)&h23;
        }
    }
    __syncthreads();   // Wr visible

#pragma unroll
    for (int kci = 0; kci < 4; kci++) {
#pragma unroll
        for (int ft = 0; ft < 8; ft++) {
            half8 a = *(const half8*)&lw[(ft * 16 + l15) * 136 + kci * 32 + quad * 8];
            acc[0][ft] = __builtin_amdgcn_mfma_f32_16x16x32_f16(a, xf0[kci], acc[0][ft], 0, 0, 0);
            acc[1][ft] = __builtin_amdgcn_mfma_f32_16x16x32_f16(a, xf1[kci], acc[1][ft], 0, 0, 0);
        }
    }

    // ---- epilogue: bias (+ normalize + relu) + store ----
#pragma unroll
    for (int nt = 0; nt < 2; nt++) {
        int node = i0 + nt * 16 + l15;
        float v[8][4];
#pragma unroll
        for (int ft = 0; ft < 8; ft++) {
            const float4 bq = *(const float4*)(bias + ft * 16 + quad * 4);
            v[ft][0] = acc[nt][ft][0] + bq.x;
            v[ft][1] = acc[nt][ft][1] + bq.y;
            v[ft][2] = acc[nt][ft][2] + bq.z;
            v[ft][3] = acc[nt][ft][3] + bq.w;
        }
        if (NORM_RELU) {
            float ss = 0.f;
#pragma unroll
            for (int ft = 0; ft < 8; ft++)
#pragma unroll
                for (int r = 0; r < 4; r++) ss = fmaf(v[ft][r], v[ft][r], ss);
            ss += __shfl_xor(ss, 16);
            ss += __shfl_xor(ss, 32);
            float inv = 1.0f / fmaxf(sqrtf(ss), 1e-12f);
#pragma unroll
            for (int ft = 0; ft < 8; ft++)
#pragma unroll
                for (int r = 0; r < 4; r++) v[ft][r] = fmaxf(v[ft][r] * inv, 0.0f);
        }
        if (node < n) {
            if (NORM_RELU) {
                __half* op = (__half*)out16 + (size_t)node * DFEAT + quad * 4;
#pragma unroll
                for (int ft = 0; ft < 8; ft++) {
                    __half2 h01 = __floats2half2_rn(v[ft][0], v[ft][1]);
                    __half2 h23 = __floats2half2_rn(v[ft][2], v[ft][3]);
                    uint2 o;
                    o.x = *(unsigned int*)&h01;
                    o.y = *(unsigned int*)&h23;
                    *(uint2*)(op + ft * 16) = o;
                }
            } else {
                float* op = out32 + (size_t)node * DFEAT + quad * 4;
#pragma unroll
                for (int ft = 0; ft < 8; ft++)
                    *(float4*)(op + ft * 16) = make_float4(v[ft][0], v[ft][1], v[ft][2], v[ft][3]);
            }
        }
    }
}

extern "C" void kernel_launch(void* const* d_in, const int* in_sizes, int n_in,
                              void* d_out, int out_size, void* d_ws, size_t ws_size,
                              hipStream_t stream) {
    const float* x = (const float*)d_in[0];
    const int* edge_index = (const int*)d_in[1];
    const float* W1l = (const float*)d_in[2];
    const float* b1 = (const float*)d_in[3];
    const float* W1r = (const float*)d_in[4];
    const float* W2l = (const float*)d_in[5];
    const float* b2 = (const float*)d_in[6];
    const float* W2r = (const float*)d_in[7];
    float* out = (float*)d_out;

    const int E = in_sizes[1] / 2;
    const int n = in_sizes[0] / DFEAT;  // 100000

    int* ws = (int*)d_ws;
    int* cnt = ws + WS_CNT;
    int* gh = ws + WS_GH;
    int* partialB = ws + WS_PARTB;
    int* offs = ws + WS_OFFS;
    int* esrc = ws + WS_ESRC;
    int2* pairs = (int2*)(ws + WS_AGGH);
    __half* aggh = (__half*)(ws + WS_AGGH);
    __half* casth = (__half*)(ws + WS_CASTH);
    uint2* zrow = (uint2*)(ws + WS_ZROW);

    const int* src = edge_index;
    const int* dst = edge_index + E;

    const int bpart = (E + SLAB - 1) / SLAB;        // 391
    const int m = NBUCK * bpart;                    // 76636
    const int blocksB = (m + 255) / 256;            // 300
    const int total4 = n * DFEAT / 4;
    const int castblocks = (total4 + 255) / 256;    // 12500

    prep_kernel<<<castblocks + bpart, 256, 0, stream>>>(x, casth, total4, dst, gh, zrow,
                                                        E, bpart, castblocks);
    scan1_kernel<<<blocksB, 256, 0, stream>>>(gh, partialB, m);
    scan2_kernel<<<1, 512, 0, stream>>>(partialB, blocksB);
    scan3_kernel<<<blocksB, 256, 0, stream>>>(gh, partialB, m);

    phase2_kernel<<<bpart, 256, 0, stream>>>(src, dst, gh, pairs, E, bpart);
    phase3_kernel<<<NBUCK, 512, 0, stream>>>(pairs, gh, cnt, offs, esrc, E, bpart, n);

    const int gemmb = (n + 127) / 128;

    // layer 1: h = relu(normalize(mean(x_h[neigh])@W1l^T + b1 + x_h@W1r^T)) -> fp16 aggh
    fused_layer_kernel<true><<<gemmb, 256, 0, stream>>>(
        casth, esrc, offs, cnt, W1l, W1r, b1, (const __half*)zrow, nullptr, aggh, n);

    // layer 2: out = mean(h[neigh])@W2l^T + b2 + h@W2r^T (fp32 to d_out)
    fused_layer_kernel<false><<<gemmb, 256, 0, stream>>>(
        aggh, esrc, offs, cnt, W2l, W2r, b2, (const __half*)zrow, out, nullptr, n);
}

// Round 5
// 341.106 us; speedup vs baseline: 1.1554x; 1.1554x over previous
//
#include <hip/hip_runtime.h>
#include <hip/hip_bf16.h>
#include <hip/hip_fp16.h>

#define N_NODES 100000
#define DFEAT 128
#define SLAB 4096         // edges per partition block
#define BSHIFT 9          // 512 nodes per bucket
#define NBUCK 196         // ceil(100000/512)

// ---------------- ws layout (4-byte units) ----------------
// cnt    [0      , 100000)   written by phase3
// w16    [100000 , 132768)   4x fp16 weight matrices (W1l,W1r,W2l,W2r), cast by prep
// bcnt   [180000 , 180196)   per-bucket edge counts (global atomics; memset to 0)
// bbase  [180200 , 180397)   exclusive scan of bcnt (+ total at [196])
// bcur   [180400 , 180596)   allocation cursors per bucket
// offs   [200000 , 300096)   written by phase3
// esrc   [300608 , 1900608)
// aggh   [1900608, 8300608)   first: int2 pairs buffer; then fp16 agg1 / h
// casth  [8300608, 14700608)  fp16 x_h, then agg2
#define WS_CNT      0
#define WS_W16      100000
#define WS_BCNT     180000
#define WS_BBASE    180200
#define WS_BCUR     180400
#define WS_OFFS     200000
#define WS_ESRC     300608
#define WS_AGGH     1900608
#define WS_CASTH    8300608

typedef _Float16 half8 __attribute__((ext_vector_type(8)));
typedef _Float16 half2v __attribute__((ext_vector_type(2)));
typedef float floatx4 __attribute__((ext_vector_type(4)));

// ---------- fused prep: cast x->fp16 + cast 4 W matrices->fp16 + slab bucket hist ----------
__global__ __launch_bounds__(256) void prep_kernel(const float* __restrict__ x,
                                                   __half* __restrict__ xh, int total4,
                                                   const int* __restrict__ dst,
                                                   int* __restrict__ bcnt,
                                                   const float* __restrict__ W1l,
                                                   const float* __restrict__ W1r,
                                                   const float* __restrict__ W2l,
                                                   const float* __restrict__ W2r,
                                                   __half* __restrict__ w16,
                                                   int E, int bpart, int castblocks) {
    __shared__ int lh[NBUCK];
    int b = blockIdx.x;
    if (b < castblocks) {
        int i = b * 256 + threadIdx.x;
        if (i < total4) {
            float4 v = ((const float4*)x)[i];
            __half2 h01 = __floats2half2_rn(v.x, v.y);
            __half2 h23 = __floats2half2_rn(v.z, v.w);
            uint2 o;
            o.x = *(unsigned int*)&h01;
            o.y = *(unsigned int*)&h23;
            ((uint2*)xh)[i] = o;
        }
        return;
    }
    if (b < castblocks + 64) {
        // cast the 4 weight matrices: 4 * 4096 float4 = 16384 float4 over 64 blocks
        int i = (b - castblocks) * 256 + threadIdx.x;   // [0, 16384)
        int m = i >> 12;                                 // matrix 0..3
        int off = i & 4095;                              // float4 index within matrix
        const float* Wp = (m == 0) ? W1l : (m == 1) ? W1r : (m == 2) ? W2l : W2r;
        float4 v = ((const float4*)Wp)[off];
        __half2 h01 = __floats2half2_rn(v.x, v.y);
        __half2 h23 = __floats2half2_rn(v.z, v.w);
        uint2 o;
        o.x = *(unsigned int*)&h01;
        o.y = *(unsigned int*)&h23;
        ((uint2*)w16)[i] = o;
        return;
    }
    int bb = b - castblocks - 64;
    for (int i = threadIdx.x; i < NBUCK; i += 256) lh[i] = 0;
    __syncthreads();
    int s0 = bb * SLAB, s1 = min(E, s0 + SLAB);
    for (int i = s0 + threadIdx.x; i < s1; i += 256)
        atomicAdd(&lh[dst[i] >> BSHIFT], 1);
    __syncthreads();
    for (int i = threadIdx.x; i < NBUCK; i += 256)
        if (lh[i] > 0) atomicAdd(&bcnt[i], lh[i]);
}

// ---------- tiny bucket scan: bcnt[196] -> bbase (exclusive), init bcur ----------
__global__ void bscan_kernel(const int* __restrict__ bcnt, int* __restrict__ bbase,
                             int* __restrict__ bcur, int E) {
    __shared__ int s[256];
    int t = threadIdx.x;
    int v = (t < NBUCK) ? bcnt[t] : 0;
    s[t] = v;
    __syncthreads();
    for (int d = 1; d < 256; d <<= 1) {
        int u = (t >= d) ? s[t - d] : 0;
        __syncthreads();
        s[t] += u;
        __syncthreads();
    }
    if (t < NBUCK) {
        int excl = s[t] - v;
        bbase[t] = excl;
        bcur[t] = excl;
    }
    if (t == 0) bbase[NBUCK] = E;
}

// ---------- phase 2: LDS counting-sort slab by bucket; grab bucket bases via atomics ----------
__global__ __launch_bounds__(256) void phase2_kernel(const int* __restrict__ src,
                                                     const int* __restrict__ dst,
                                                     int* __restrict__ bcur,
                                                     int2* __restrict__ pairs,
                                                     int E) {
    __shared__ int lbase[NBUCK];
    __shared__ int lcur[NBUCK];
    __shared__ int lgb[NBUCK];
    __shared__ int sc[256];
    __shared__ int2 lp[SLAB];   // 32 KB
    int b = blockIdx.x;
    int t = threadIdx.x;
    for (int i = t; i < NBUCK; i += 256) lbase[i] = 0;
    __syncthreads();
    int s0 = b * SLAB, s1 = min(E, s0 + SLAB);
    for (int i = s0 + t; i < s1; i += 256)
        atomicAdd(&lbase[dst[i] >> BSHIFT], 1);
    __syncthreads();
    int v = (t < NBUCK) ? lbase[t] : 0;
    sc[t] = v;
    __syncthreads();
    for (int d = 1; d < 256; d <<= 1) {
        int u = (t >= d) ? sc[t - d] : 0;
        __syncthreads();
        sc[t] += u;
        __syncthreads();
    }
    if (t < NBUCK) {
        int excl = sc[t] - v;
        lbase[t] = excl;
        lcur[t] = excl;
        lgb[t] = (v > 0) ? atomicAdd(&bcur[t], v) : 0;   // block's base within bucket
    }
    __syncthreads();
    for (int i = s0 + t; i < s1; i += 256) {
        int d = dst[i];
        int s = src[i];
        int bk = d >> BSHIFT;
        int pos = atomicAdd(&lcur[bk], 1);
        lp[pos] = make_int2(s, d);
    }
    __syncthreads();
    int m = s1 - s0;
    for (int i = t; i < m; i += 256) {
        int2 p = lp[i];
        int bk = p.y >> BSHIFT;
        pairs[lgb[bk] + (i - lbase[bk])] = p;
    }
}

// ---------- phase 3: per-bucket node hist (LDS) + scan -> cnt/offs + CSR finalize ----------
__global__ __launch_bounds__(512) void phase3_kernel(const int2* __restrict__ pairs,
                                                     const int* __restrict__ bbase,
                                                     int* __restrict__ cnt,
                                                     int* __restrict__ offs,
                                                     int* __restrict__ esrc,
                                                     int n) {
    __shared__ int lcnt[512];
    __shared__ int sc[512];
    __shared__ int lexcl[512];
    int g = blockIdx.x;
    int node0 = g << BSHIFT;
    int t = threadIdx.x;
    lcnt[t] = 0;
    __syncthreads();
    int S = bbase[g];
    int Eg = bbase[g + 1];
    for (int i = S + t; i < Eg; i += 512)
        atomicAdd(&lcnt[pairs[i].y - node0], 1);
    __syncthreads();
    int v = lcnt[t];
    sc[t] = v;
    __syncthreads();
    for (int d = 1; d < 512; d <<= 1) {
        int u = (t >= d) ? sc[t - d] : 0;
        __syncthreads();
        sc[t] += u;
        __syncthreads();
    }
    int excl = sc[t] - v;
    lexcl[t] = excl;
    int nd = node0 + t;
    if (nd < n) {
        cnt[nd] = v;
        offs[nd] = S + excl;
    }
    __syncthreads();
    for (int i = S + t; i < Eg; i += 512) {
        int2 p = pairs[i];
        int pos = atomicAdd(&lexcl[p.y - node0], 1);
        esrc[S + pos] = p.x;
    }
}

// ---------- aggregate: one 16-lane group per node (4 nodes/wave) — round-3 proven ----------
#define ACC(c, r)                        \
    s[c][0] += *(half2v*)&(r).x;         \
    s[c][1] += *(half2v*)&(r).y;         \
    s[c][2] += *(half2v*)&(r).z;         \
    s[c][3] += *(half2v*)&(r).w;

__global__ void aggregate_kernel(const __half* __restrict__ feat, const int* __restrict__ esrc,
                                 const int* __restrict__ offs, const int* __restrict__ cnt,
                                 __half* __restrict__ agg, int n) {
    int wid = (blockIdx.x * blockDim.x + threadIdx.x) >> 6;
    int lane = threadIdx.x & 63;
    int grp = lane >> 4;            // 0..3: node slot within wave
    int l15 = lane & 15;
    int node = wid * 4 + grp;
    if (node >= n) return;
    int beg = offs[node];
    int deg = cnt[node];
    const _Float16* fbase = (const _Float16*)feat + l15 * 8;
    const int* ep = esrc + beg;

    half2v s[4][4];
#pragma unroll
    for (int c = 0; c < 4; c++)
#pragma unroll
        for (int k = 0; k < 4; k++) s[c][k] = (half2v)(_Float16)0;

    int j = 0;
    for (; j + 8 <= deg; j += 8) {
        int i0 = ep[j + 0], i1 = ep[j + 1], i2 = ep[j + 2], i3 = ep[j + 3];
        int i4 = ep[j + 4], i5 = ep[j + 5], i6 = ep[j + 6], i7 = ep[j + 7];
        uint4 r0 = *(const uint4*)(fbase + (size_t)i0 * DFEAT);
        uint4 r1 = *(const uint4*)(fbase + (size_t)i1 * DFEAT);
        uint4 r2 = *(const uint4*)(fbase + (size_t)i2 * DFEAT);
        uint4 r3 = *(const uint4*)(fbase + (size_t)i3 * DFEAT);
        uint4 r4 = *(const uint4*)(fbase + (size_t)i4 * DFEAT);
        uint4 r5 = *(const uint4*)(fbase + (size_t)i5 * DFEAT);
        uint4 r6 = *(const uint4*)(fbase + (size_t)i6 * DFEAT);
        uint4 r7 = *(const uint4*)(fbase + (size_t)i7 * DFEAT);
        ACC(0, r0) ACC(1, r1) ACC(2, r2) ACC(3, r3)
        ACC(0, r4) ACC(1, r5) ACC(2, r6) ACC(3, r7)
    }
    for (; j + 4 <= deg; j += 4) {
        int i0 = ep[j + 0], i1 = ep[j + 1], i2 = ep[j + 2], i3 = ep[j + 3];
        uint4 r0 = *(const uint4*)(fbase + (size_t)i0 * DFEAT);
        uint4 r1 = *(const uint4*)(fbase + (size_t)i1 * DFEAT);
        uint4 r2 = *(const uint4*)(fbase + (size_t)i2 * DFEAT);
        uint4 r3 = *(const uint4*)(fbase + (size_t)i3 * DFEAT);
        ACC(0, r0) ACC(1, r1) ACC(2, r2) ACC(3, r3)
    }
    if (j < deg) {
        int rem = deg - j;
        int i0 = ep[j];
        int i1 = ep[j + (rem > 1 ? 1 : 0)];
        int i2 = ep[j + (rem > 2 ? 2 : 0)];
        uint4 r0 = *(const uint4*)(fbase + (size_t)i0 * DFEAT);
        uint4 r1 = *(const uint4*)(fbase + (size_t)i1 * DFEAT);
        uint4 r2 = *(const uint4*)(fbase + (size_t)i2 * DFEAT);
        if (rem < 2) { r1.x = 0u; r1.y = 0u; r1.z = 0u; r1.w = 0u; }
        if (rem < 3) { r2.x = 0u; r2.y = 0u; r2.z = 0u; r2.w = 0u; }
        ACC(0, r0) ACC(1, r1) ACC(2, r2)
    }

    float scale = 1.0f / fmaxf((float)deg, 1.0f);
    float a[8];
#pragma unroll
    for (int k = 0; k < 4; k++) {
        a[2 * k]     = ((float)s[0][k].x + (float)s[1][k].x) + ((float)s[2][k].x + (float)s[3][k].x);
        a[2 * k + 1] = ((float)s[0][k].y + (float)s[1][k].y) + ((float)s[2][k].y + (float)s[3][k].y);
    }
    __half2 h0 = __floats2half2_rn(a[0] * scale, a[1] * scale);
    __half2 h1 = __floats2half2_rn(a[2] * scale, a[3] * scale);
    __half2 h2 = __floats2half2_rn(a[4] * scale, a[5] * scale);
    __half2 h3 = __floats2half2_rn(a[6] * scale, a[7] * scale);
    uint4 o;
    o.x = *(unsigned int*)&h0;
    o.y = *(unsigned int*)&h1;
    o.z = *(unsigned int*)&h2;
    o.w = *(unsigned int*)&h3;
    *(uint4*)(agg + (size_t)node * DFEAT + l15 * 8) = o;
}

// ---------- MFMA dual-GEMM: 64-node blocks (wave=16 nodes), fp16 W pre-cast, prefetch ----------
template <bool NORM_RELU>
__global__ __launch_bounds__(256) void gemm64_kernel(
    const __half* __restrict__ A1_, const __half* __restrict__ A2_,
    const __half* __restrict__ Wl16, const __half* __restrict__ Wr16,
    const float* __restrict__ bias, float* __restrict__ out32,
    __half* __restrict__ out16, int n) {
    __shared__ __align__(16) _Float16 lw[128 * 136];   // 34.8 KB

    const _Float16* A1 = (const _Float16*)A1_;
    const _Float16* A2 = (const _Float16*)A2_;
    const _Float16* wl = (const _Float16*)Wl16;
    const _Float16* wr = (const _Float16*)Wr16;

    const int lane = threadIdx.x & 63;
    const int w = threadIdx.x >> 6;       // wave 0..3
    const int quad = lane >> 4;
    const int l15 = lane & 15;
    const int i0 = blockIdx.x * 64 + w * 16;
    int r = i0 + l15;
    if (r >= n) r = n - 1;
    const int kq = quad * 8;

    // prefetch B-fragments (agg rows) so they fly during Wl staging
    half8 bf[4];
#pragma unroll
    for (int k = 0; k < 4; k++)
        bf[k] = *(const half8*)(A1 + (size_t)r * DFEAT + k * 32 + kq);

    // stage Wl (fp16 copy, 8 uint4/thread)
    {
        int t = threadIdx.x;
        int row = t >> 1;
        int cb = (t & 1) * 64;
        const uint4* sp = (const uint4*)(wl + row * DFEAT + cb);
        uint4* dp = (uint4*)&lw[row * 136 + cb];
#pragma unroll
        for (int q = 0; q < 8; q++) dp[q] = sp[q];
    }
    __syncthreads();

    floatx4 acc[8];
#pragma unroll
    for (int ft = 0; ft < 8; ft++) acc[ft] = (floatx4){0.f, 0.f, 0.f, 0.f};

#pragma unroll
    for (int kci = 0; kci < 4; kci++) {
#pragma unroll
        for (int ft = 0; ft < 8; ft++) {
            half8 a = *(const half8*)&lw[(ft * 16 + l15) * 136 + kci * 32 + kq];
            acc[ft] = __builtin_amdgcn_mfma_f32_16x16x32_f16(a, bf[kci], acc[ft], 0, 0, 0);
        }
    }

    // prefetch root (self) fragments; they fly across the barrier/staging
    half8 xf[4];
#pragma unroll
    for (int k = 0; k < 4; k++)
        xf[k] = *(const half8*)(A2 + (size_t)r * DFEAT + k * 32 + kq);

    __syncthreads();   // all waves done reading Wl
    // stage Wr
    {
        int t = threadIdx.x;
        int row = t >> 1;
        int cb = (t & 1) * 64;
        const uint4* sp = (const uint4*)(wr + row * DFEAT + cb);
        uint4* dp = (uint4*)&lw[row * 136 + cb];
#pragma unroll
        for (int q = 0; q < 8; q++) dp[q] = sp[q];
    }
    __syncthreads();

#pragma unroll
    for (int kci = 0; kci < 4; kci++) {
#pragma unroll
        for (int ft = 0; ft < 8; ft++) {
            half8 a = *(const half8*)&lw[(ft * 16 + l15) * 136 + kci * 32 + kq];
            acc[ft] = __builtin_amdgcn_mfma_f32_16x16x32_f16(a, xf[kci], acc[ft], 0, 0, 0);
        }
    }

    // ---- epilogue: bias (+ normalize + relu) + store ----
    int node = i0 + l15;
    float v[8][4];
#pragma unroll
    for (int ft = 0; ft < 8; ft++) {
        const float4 bq = *(const float4*)(bias + ft * 16 + quad * 4);
        v[ft][0] = acc[ft][0] + bq.x;
        v[ft][1] = acc[ft][1] + bq.y;
        v[ft][2] = acc[ft][2] + bq.z;
        v[ft][3] = acc[ft][3] + bq.w;
    }
    if (NORM_RELU) {
        float ss = 0.f;
#pragma unroll
        for (int ft = 0; ft < 8; ft++)
#pragma unroll
            for (int q = 0; q < 4; q++) ss = fmaf(v[ft][q], v[ft][q], ss);
        ss += __shfl_xor(ss, 16);
        ss += __shfl_xor(ss, 32);
        float inv = 1.0f / fmaxf(sqrtf(ss), 1e-12f);
#pragma unroll
        for (int ft = 0; ft < 8; ft++)
#pragma unroll
            for (int q = 0; q < 4; q++) v[ft][q] = fmaxf(v[ft][q] * inv, 0.0f);
    }
    if (node < n) {
        if (NORM_RELU) {
            __half* op = (__half*)out16 + (size_t)node * DFEAT + quad * 4;
#pragma unroll
            for (int ft = 0; ft < 8; ft++) {
                __half2 h01 = __floats2half2_rn(v[ft][0], v[ft][1]);
                __half2 h23 = __floats2half2_rn(v[ft][2], v[ft][3]);
                uint2 o;
                o.x = *(unsigned int*)&h01;
                o.y = *(unsigned int*)&h23;
                *(uint2*)(op + ft * 16) = o;
            }
        } else {
            float* op = out32 + (size_t)node * DFEAT + quad * 4;
#pragma unroll
            for (int ft = 0; ft < 8; ft++)
                *(float4*)(op + ft * 16) = make_float4(v[ft][0], v[ft][1], v[ft][2], v[ft][3]);
        }
    }
}

extern "C" void kernel_launch(void* const* d_in, const int* in_sizes, int n_in,
                              void* d_out, int out_size, void* d_ws, size_t ws_size,
                              hipStream_t stream) {
    const float* x = (const float*)d_in[0];
    const int* edge_index = (const int*)d_in[1];
    const float* W1l = (const float*)d_in[2];
    const float* b1 = (const float*)d_in[3];
    const float* W1r = (const float*)d_in[4];
    const float* W2l = (const float*)d_in[5];
    const float* b2 = (const float*)d_in[6];
    const float* W2r = (const float*)d_in[7];
    float* out = (float*)d_out;

    const int E = in_sizes[1] / 2;
    const int n = in_sizes[0] / DFEAT;  // 100000

    int* ws = (int*)d_ws;
    int* cnt = ws + WS_CNT;
    __half* w16 = (__half*)(ws + WS_W16);
    int* bcnt = ws + WS_BCNT;
    int* bbase = ws + WS_BBASE;
    int* bcur = ws + WS_BCUR;
    int* offs = ws + WS_OFFS;
    int* esrc = ws + WS_ESRC;
    int2* pairs = (int2*)(ws + WS_AGGH);
    __half* aggh = (__half*)(ws + WS_AGGH);
    __half* casth = (__half*)(ws + WS_CASTH);

    const int* src = edge_index;
    const int* dst = edge_index + E;

    const int bpart = (E + SLAB - 1) / SLAB;        // 391
    const int total4 = n * DFEAT / 4;
    const int castblocks = (total4 + 255) / 256;    // 12500

    // per-matrix fp16 views (order: W1l, W1r, W2l, W2r)
    __half* w1l16 = w16;
    __half* w1r16 = w16 + 16384;
    __half* w2l16 = w16 + 32768;
    __half* w2r16 = w16 + 49152;

    hipMemsetAsync(bcnt, 0, NBUCK * sizeof(int), stream);

    prep_kernel<<<castblocks + 64 + bpart, 256, 0, stream>>>(
        x, casth, total4, dst, bcnt, W1l, W1r, W2l, W2r, w16, E, bpart, castblocks);
    bscan_kernel<<<1, 256, 0, stream>>>(bcnt, bbase, bcur, E);
    phase2_kernel<<<bpart, 256, 0, stream>>>(src, dst, bcur, pairs, E);
    phase3_kernel<<<NBUCK, 512, 0, stream>>>(pairs, bbase, cnt, offs, esrc, n);

    const int nwaves = (n + 3) / 4;
    const int aggb = (nwaves * 64 + 255) / 256;     // 6250
    const int gemmb = (n + 63) / 64;                // 1563

    // layer 1: agg(x_h) -> aggh; h = relu(normalize(aggh@W1l^T + b1 + x_h@W1r^T)) -> fp16 aggh
    aggregate_kernel<<<aggb, 256, 0, stream>>>(casth, esrc, offs, cnt, aggh, n);
    gemm64_kernel<true><<<gemmb, 256, 0, stream>>>(aggh, casth, w1l16, w1r16, b1,
                                                   nullptr, aggh, n);

    // layer 2: agg(h) -> casth; out = casth@W2l^T + b2 + h@W2r^T (fp32 to d_out)
    aggregate_kernel<<<aggb, 256, 0, stream>>>(aggh, esrc, offs, cnt, casth, n);
    gemm64_kernel<false><<<gemmb, 256, 0, stream>>>(casth, aggh, w2l16, w2r16, b2,
                                                    out, nullptr, n);
}